// Round 15
// baseline (277.122 us; speedup 1.0000x reference)
//
#include <hip/hip_runtime.h>

// RankModelF: BATCH=1e6 rows. prob[k] = c_i * s_j, c_i = s_i/(T*(T-s_i)).
// R8/R12 A/B: nt-vs-plain stores and strided-vs-unrolled writes both NEUTRAL
// (kernel ~65-110us vs ~42us ideal). New probe: drop the s_sv LDS transpose +
// 2nd barrier; keep s,c in REGISTERS, each thread stores its own row's
// 14 float4 (224B/lane stride; wave burst covers contiguous 14KB, L2 merges).
// LDS 26.9->9.5KB => 8 blocks/CU. 3-way probe: win => LDS/barrier was limiter;
// regression => lane-contiguous stores were load-bearing; neutral => floor.

#define BATCH_N   1000000
#define ROWS      256      // rows per block
#define TPB       256
#define NOUT      56       // permutations(8,2)

typedef float f32x4 __attribute__((ext_vector_type(4)));

__global__ __launch_bounds__(TPB) void rank_model_kernel(
    const int*  __restrict__ stim,   // (BATCH, 9) int32
    const float* __restrict__ emb,   // (21, 3) f32
    float*      __restrict__ out)    // (BATCH, 56) f32
{
    __shared__ float s_emb[21 * 3];     // 63 floats
    __shared__ int   s_stim[ROWS * 9];  // staged indices (coalesced global read)

    const unsigned t     = threadIdx.x;
    const unsigned row0  = blockIdx.x * ROWS;
    const int      nrows = min((int)ROWS, BATCH_N - (int)row0);

    if (t < 63) s_emb[t] = emb[t];

    const int nInts = nrows * 9;
    for (int i = (int)t; i < nInts; i += TPB)
        s_stim[i] = stim[(size_t)row0 * 9 + i];
    __syncthreads();

    if ((int)t < nrows) {
        const int* st = &s_stim[t * 9];
        const int qi = st[0];
        const float qx = s_emb[qi * 3 + 0];
        const float qy = s_emb[qi * 3 + 1];
        const float qz = s_emb[qi * 3 + 2];

        float s[8];
        float total = 0.0f;
#pragma unroll
        for (int j = 0; j < 8; ++j) {
            const int ri = st[1 + j];
            const float dx = qx - s_emb[ri * 3 + 0];
            const float dy = qy - s_emb[ri * 3 + 1];
            const float dz = qz - s_emb[ri * 3 + 2];
            const float d  = sqrtf(dx * dx + dy * dy + dz * dz);
            s[j] = expf(-10.0f * d) + 0.001f;
            total += s[j];
        }

        float c[8];
#pragma unroll
        for (int j = 0; j < 8; ++j)
            c[j] = s[j] / (total * (total - s[j]));

        // Build the 56 outputs in registers (all indices compile-time).
        float vbuf[NOUT];
        int k = 0;
#pragma unroll
        for (int i = 0; i < 8; ++i) {
#pragma unroll
            for (int j = 0; j < 8; ++j) {
                if (j == i) continue;
                vbuf[k++] = c[i] * s[j];
            }
        }

        // 14 x dwordx4 stores to this thread's own row (16B-aligned: 56*4=224B).
        f32x4* o4 = (f32x4*)(out + ((size_t)row0 + t) * NOUT);
#pragma unroll
        for (int m = 0; m < NOUT / 4; ++m) {
            f32x4 v;
            v[0] = vbuf[4 * m + 0];
            v[1] = vbuf[4 * m + 1];
            v[2] = vbuf[4 * m + 2];
            v[3] = vbuf[4 * m + 3];
            o4[m] = v;
        }
    }
}

extern "C" void kernel_launch(void* const* d_in, const int* in_sizes, int n_in,
                              void* d_out, int out_size, void* d_ws, size_t ws_size,
                              hipStream_t stream) {
    const int*   stim = (const int*)d_in[0];    // stimulus_set (BATCH,9) int32
    const float* emb  = (const float*)d_in[1];  // embedding (21,3) f32
    float*       out  = (float*)d_out;          // (BATCH,56) f32

    const int grid = (BATCH_N + ROWS - 1) / ROWS;  // 3907
    rank_model_kernel<<<grid, TPB, 0, stream>>>(stim, emb, out);
}